// Round 1
// baseline (327.928 us; speedup 1.0000x reference)
//
#include <hip/hip_runtime.h>

#define NB 4
#define NS 2048
#define ND 512
#define NH 8
#define NDK 64

typedef __attribute__((ext_vector_type(8))) short bf16x8;
typedef __attribute__((ext_vector_type(4))) float f32x4;

__device__ inline f32x4 mfma16(bf16x8 a, bf16x8 b, f32x4 c) {
    return __builtin_amdgcn_mfma_f32_16x16x32_bf16(a, b, c, 0, 0, 0);
}

__device__ inline unsigned short f2bf(float f) {
    unsigned u = __float_as_uint(f);
    unsigned r = u + 0x7FFFu + ((u >> 16) & 1u);
    return (unsigned short)(r >> 16);
}
__device__ inline float bf2f(unsigned short h) {
    return __uint_as_float(((unsigned)h) << 16);
}
__device__ inline void splitf(float x, short& hi, short& lo) {
    unsigned short h = f2bf(x);
    hi = (short)h;
    lo = (short)f2bf(x - bf2f(h));
}

// ---------------------------------------------------------------------------
// Kernel 1: per-head projections.
//   z=0: Qh = Q @ WQ[h]  -> qhi/qlo (split bf16 pair), layout [B,H,S,DK]
//   z=1: Kh = K @ WK[h]  -> khi/klo
//   z=2: Vh = V @ WV[h]  -> vt, bf16, TRANSPOSED layout [B,H,DK,S]
// Tile: 128 rows (of flattened b*s) x 64 cols (=DK). 4 waves, each 32x64.
// Split 3-term MFMA for z<2 (precision-critical), single term for V.
// ---------------------------------------------------------------------------
__global__ __launch_bounds__(256) void proj_kernel(
    const float* __restrict__ Q, const float* __restrict__ K, const float* __restrict__ V,
    const float* __restrict__ WQ, const float* __restrict__ WK, const float* __restrict__ WV,
    short* __restrict__ qhi, short* __restrict__ qlo,
    short* __restrict__ khi, short* __restrict__ klo,
    short* __restrict__ vt)
{
    const int mt = blockIdx.x;          // 0..63 (m-tile of 128 rows)
    const int h  = blockIdx.y;          // head
    const int z  = blockIdx.z;          // 0=Q 1=K 2=V
    const int m0 = mt * 128;
    const int tid = threadIdx.x;
    const int w = tid >> 6, lane = tid & 63, c = lane & 15, g = lane >> 4;

    const float* X = (z == 0) ? Q : (z == 1) ? K : V;
    const float* W = ((z == 0) ? WQ : (z == 1) ? WK : WV) + (size_t)h * ND * NDK;

    __shared__ __align__(16) short smem[15360];
    short* xhi  = smem;                 // [128][40]  (32 k + 8 pad)
    short* xlo  = smem + 5120;
    short* wthi = smem + 10240;         // [64][40]   W^T tile: [n][k]
    short* wtlo = smem + 12800;

    f32x4 acc[2][4];
    #pragma unroll
    for (int i = 0; i < 2; i++)
        #pragma unroll
        for (int j = 0; j < 4; j++) acc[i][j] = f32x4{0.f, 0.f, 0.f, 0.f};

    for (int k0 = 0; k0 < ND; k0 += 32) {
        // --- stage X[128][32] f32 -> split bf16 hi/lo ---
        {
            int r = tid >> 1, kq = (tid & 1) * 16;
            const float* src = X + (size_t)(m0 + r) * ND + k0 + kq;
            short hv[16], lv[16];
            #pragma unroll
            for (int i = 0; i < 4; i++) {
                float4 f = ((const float4*)src)[i];
                splitf(f.x, hv[4*i+0], lv[4*i+0]);
                splitf(f.y, hv[4*i+1], lv[4*i+1]);
                splitf(f.z, hv[4*i+2], lv[4*i+2]);
                splitf(f.w, hv[4*i+3], lv[4*i+3]);
            }
            bf16x8 vh0, vh1, vl0, vl1;
            #pragma unroll
            for (int i = 0; i < 8; i++) { vh0[i]=hv[i]; vh1[i]=hv[8+i]; vl0[i]=lv[i]; vl1[i]=lv[8+i]; }
            *(bf16x8*)&xhi[r*40 + kq]     = vh0;
            *(bf16x8*)&xhi[r*40 + kq + 8] = vh1;
            *(bf16x8*)&xlo[r*40 + kq]     = vl0;
            *(bf16x8*)&xlo[r*40 + kq + 8] = vl1;
        }
        // --- stage W[32][64] f32 -> transposed split bf16 [64][40] ---
        #pragma unroll
        for (int i = 0; i < 2; i++) {
            int idx = tid * 2 + i;          // 0..511
            int kr = idx >> 4, c4 = (idx & 15) * 4;
            float4 f = *(const float4*)(W + (size_t)(k0 + kr) * NDK + c4);
            short hh, ll;
            splitf(f.x, hh, ll); wthi[(c4+0)*40 + kr] = hh; wtlo[(c4+0)*40 + kr] = ll;
            splitf(f.y, hh, ll); wthi[(c4+1)*40 + kr] = hh; wtlo[(c4+1)*40 + kr] = ll;
            splitf(f.z, hh, ll); wthi[(c4+2)*40 + kr] = hh; wtlo[(c4+2)*40 + kr] = ll;
            splitf(f.w, hh, ll); wthi[(c4+3)*40 + kr] = hh; wtlo[(c4+3)*40 + kr] = ll;
        }
        __syncthreads();

        bf16x8 ah[2], al[2];
        ah[0] = *(bf16x8*)&xhi[(32*w +      c)*40 + 8*g];
        ah[1] = *(bf16x8*)&xhi[(32*w + 16 + c)*40 + 8*g];
        al[0] = *(bf16x8*)&xlo[(32*w +      c)*40 + 8*g];
        al[1] = *(bf16x8*)&xlo[(32*w + 16 + c)*40 + 8*g];
        #pragma unroll
        for (int nf = 0; nf < 4; nf++) {
            bf16x8 bh = *(bf16x8*)&wthi[(c + 16*nf)*40 + 8*g];
            bf16x8 bl = *(bf16x8*)&wtlo[(c + 16*nf)*40 + 8*g];
            #pragma unroll
            for (int mi = 0; mi < 2; mi++) {
                acc[mi][nf] = mfma16(ah[mi], bh, acc[mi][nf]);
                if (z < 2) {  // split terms only where precision matters (Q,K)
                    acc[mi][nf] = mfma16(ah[mi], bl, acc[mi][nf]);
                    acc[mi][nf] = mfma16(al[mi], bh, acc[mi][nf]);
                }
            }
        }
        __syncthreads();
    }

    if (z < 2) {
        short* ohi = (z == 0) ? qhi : khi;
        short* olo = (z == 0) ? qlo : klo;
        #pragma unroll
        for (int mi = 0; mi < 2; mi++)
            #pragma unroll
            for (int nf = 0; nf < 4; nf++)
                #pragma unroll
                for (int r = 0; r < 4; r++) {
                    int row = m0 + 32*w + 16*mi + 4*g + r;
                    int b = row >> 11, s = row & 2047;
                    int col = c + 16*nf;
                    size_t o = ((size_t)(b * NH + h) * NS + s) * NDK + col;
                    short hh, ll; splitf(acc[mi][nf][r], hh, ll);
                    ohi[o] = hh; olo[o] = ll;
                }
    } else {
        // V: transpose tile through LDS, write [B,H,DK,S]
        short* vtile = smem;                 // [128][72]
        #pragma unroll
        for (int mi = 0; mi < 2; mi++)
            #pragma unroll
            for (int nf = 0; nf < 4; nf++)
                #pragma unroll
                for (int r = 0; r < 4; r++) {
                    int rl = 32*w + 16*mi + 4*g + r;
                    vtile[rl*72 + c + 16*nf] = (short)f2bf(acc[mi][nf][r]);
                }
        __syncthreads();
        int dk = tid >> 2, sc4 = (tid & 3) * 32;
        int b = m0 >> 11;
        int sbase = (m0 & 2047) + sc4;
        short* dst = vt + ((size_t)(b * NH + h) * NDK + dk) * NS + sbase;
        #pragma unroll
        for (int ch = 0; ch < 4; ch++) {
            bf16x8 vv;
            #pragma unroll
            for (int i = 0; i < 8; i++) vv[i] = vtile[(sc4 + ch*8 + i)*72 + dk];
            *(bf16x8*)&dst[ch*8] = vv;
        }
    }
}

// ---------------------------------------------------------------------------
// Kernel 2: flash attention per (b,h). Block = 64 q-rows (4 waves x 16q).
// K/V staged in LDS in 64-s tiles; scores via split 3-term MFMA; online
// softmax in f32; P -> per-wave LDS (bf16) -> A-fragments for PV MFMA.
// ---------------------------------------------------------------------------
__global__ __launch_bounds__(256) void attn_kernel(
    const short* __restrict__ qhi, const short* __restrict__ qlo,
    const short* __restrict__ khi, const short* __restrict__ klo,
    const short* __restrict__ vt, short* __restrict__ ao)
{
    const int bh = blockIdx.x;            // b*NH + h  (x-fastest -> same-bh on same XCD)
    const int qb = blockIdx.y * 64;
    const int tid = threadIdx.x;
    const int w = tid >> 6, lane = tid & 63, c = lane & 15, g = lane >> 4;

    __shared__ __align__(16) short kldsh[64*72];
    __shared__ __align__(16) short kldsl[64*72];
    __shared__ __align__(16) short vlds [64*72];
    __shared__ __align__(16) short pbuf [4*16*72];
    short* pw = pbuf + w * 16 * 72;

    // Q fragments (hi/lo, 2 k-steps) held in registers for the whole pass
    bf16x8 qh[2], ql[2];
    {
        const size_t qrow = ((size_t)bh * NS + qb + 16*w + c) * NDK;
        qh[0] = *(const bf16x8*)&qhi[qrow + 8*g];
        qh[1] = *(const bf16x8*)&qhi[qrow + 32 + 8*g];
        ql[0] = *(const bf16x8*)&qlo[qrow + 8*g];
        ql[1] = *(const bf16x8*)&qlo[qrow + 32 + 8*g];
    }

    float mrow[4], lrow[4];
    f32x4 acc[4];
    #pragma unroll
    for (int r = 0; r < 4; r++) { mrow[r] = -1e30f; lrow[r] = 0.f; }
    #pragma unroll
    for (int nf = 0; nf < 4; nf++) acc[nf] = f32x4{0.f, 0.f, 0.f, 0.f};

    for (int s0 = 0; s0 < NS; s0 += 64) {
        {   // stage K hi/lo [64 s][64 dk] and V^T [64 dk][64 s]
            int row = tid >> 2, cq = (tid & 3) * 16;
            size_t go = ((size_t)bh * NS + s0 + row) * NDK + cq;
            *(bf16x8*)&kldsh[row*72 + cq]     = *(const bf16x8*)&khi[go];
            *(bf16x8*)&kldsh[row*72 + cq + 8] = *(const bf16x8*)&khi[go + 8];
            *(bf16x8*)&kldsl[row*72 + cq]     = *(const bf16x8*)&klo[go];
            *(bf16x8*)&kldsl[row*72 + cq + 8] = *(const bf16x8*)&klo[go + 8];
            size_t gv = ((size_t)bh * NDK + row) * NS + s0 + cq;
            *(bf16x8*)&vlds[row*72 + cq]      = *(const bf16x8*)&vt[gv];
            *(bf16x8*)&vlds[row*72 + cq + 8]  = *(const bf16x8*)&vt[gv + 8];
        }
        __syncthreads();

        // scores: S_tile[16q x 64s], split 3-term MFMA over dk=64 (2 k-steps)
        f32x4 sc[4];
        #pragma unroll
        for (int sf = 0; sf < 4; sf++) {
            sc[sf] = f32x4{0.f, 0.f, 0.f, 0.f};
            #pragma unroll
            for (int ks = 0; ks < 2; ks++) {
                bf16x8 kh = *(bf16x8*)&kldsh[(c + 16*sf)*72 + ks*32 + 8*g];
                bf16x8 kl = *(bf16x8*)&kldsl[(c + 16*sf)*72 + ks*32 + 8*g];
                sc[sf] = mfma16(qh[ks], kh, sc[sf]);
                sc[sf] = mfma16(qh[ks], kl, sc[sf]);
                sc[sf] = mfma16(ql[ks], kh, sc[sf]);
            }
        }

        // online softmax (rows live on lanes: row = 4g+r, col = c+16sf)
        float mnew[4], fac[4], rs[4];
        #pragma unroll
        for (int r = 0; r < 4; r++) {
            float v = -1e30f;
            #pragma unroll
            for (int sf = 0; sf < 4; sf++) { sc[sf][r] *= 0.125f; v = fmaxf(v, sc[sf][r]); }
            #pragma unroll
            for (int off = 1; off < 16; off <<= 1) v = fmaxf(v, __shfl_xor(v, off));
            mnew[r] = fmaxf(mrow[r], v);
            fac[r]  = __expf(mrow[r] - mnew[r]);
            mrow[r] = mnew[r];
            rs[r] = 0.f;
        }
        #pragma unroll
        for (int sf = 0; sf < 4; sf++)
            #pragma unroll
            for (int r = 0; r < 4; r++) {
                float p = __expf(sc[sf][r] - mnew[r]);
                rs[r] += p;
                pw[(4*g + r)*72 + c + 16*sf] = (short)f2bf(p);
            }
        #pragma unroll
        for (int r = 0; r < 4; r++) {
            float t = rs[r];
            #pragma unroll
            for (int off = 1; off < 16; off <<= 1) t += __shfl_xor(t, off);
            lrow[r] = lrow[r] * fac[r] + t;
        }
        #pragma unroll
        for (int nf = 0; nf < 4; nf++)
            #pragma unroll
            for (int r = 0; r < 4; r++) acc[nf][r] *= fac[r];

        // PV: out[16q x 64dk] += P[16q x 64s] @ V[64s x 64dk]
        #pragma unroll
        for (int ks = 0; ks < 2; ks++) {
            bf16x8 pa = *(bf16x8*)&pw[c*72 + ks*32 + 8*g];
            #pragma unroll
            for (int nf = 0; nf < 4; nf++) {
                bf16x8 vv = *(bf16x8*)&vlds[(c + 16*nf)*72 + ks*32 + 8*g];
                acc[nf] = mfma16(pa, vv, acc[nf]);
            }
        }
        __syncthreads();
    }

    // epilogue: divide by row sums, write concat-head layout [B,S,H*DK] bf16
    const int b = bh >> 3, h = bh & 7;
    #pragma unroll
    for (int r = 0; r < 4; r++) {
        float inv = 1.f / lrow[r];
        int q = qb + 16*w + 4*g + r;
        size_t o = ((size_t)b * NS + q) * ND + h * NDK;
        #pragma unroll
        for (int nf = 0; nf < 4; nf++)
            ao[o + c + 16*nf] = (short)f2bf(acc[nf][r] * inv);
    }
}

// ---------------------------------------------------------------------------
// Kernel 3: output projection  out[8192x512] = ao(bf16) @ WO(f32->bf16)
// Tile 128x64, 4 waves x (32x64). Single bf16 MFMA.
// ---------------------------------------------------------------------------
__global__ __launch_bounds__(256) void oproj_kernel(
    const short* __restrict__ ao, const float* __restrict__ WO, float* __restrict__ out)
{
    const int mb = blockIdx.x * 128, nb = blockIdx.y * 64;
    const int tid = threadIdx.x;
    const int w = tid >> 6, lane = tid & 63, c = lane & 15, g = lane >> 4;

    __shared__ __align__(16) short xlds[128*40];
    __shared__ __align__(16) short wt[64*40];

    f32x4 acc[2][4];
    #pragma unroll
    for (int i = 0; i < 2; i++)
        #pragma unroll
        for (int j = 0; j < 4; j++) acc[i][j] = f32x4{0.f, 0.f, 0.f, 0.f};

    for (int k0 = 0; k0 < ND; k0 += 32) {
        {
            int r = tid >> 1, kq = (tid & 1) * 16;
            const short* src = ao + (size_t)(mb + r) * ND + k0 + kq;
            *(bf16x8*)&xlds[r*40 + kq]     = *(const bf16x8*)src;
            *(bf16x8*)&xlds[r*40 + kq + 8] = *(const bf16x8*)(src + 8);
        }
        #pragma unroll
        for (int i = 0; i < 2; i++) {
            int idx = tid * 2 + i;
            int kr = idx >> 4, c4 = (idx & 15) * 4;
            float4 f = *(const float4*)&WO[(size_t)(k0 + kr) * ND + nb + c4];
            wt[(c4+0)*40 + kr] = (short)f2bf(f.x);
            wt[(c4+1)*40 + kr] = (short)f2bf(f.y);
            wt[(c4+2)*40 + kr] = (short)f2bf(f.z);
            wt[(c4+3)*40 + kr] = (short)f2bf(f.w);
        }
        __syncthreads();
        bf16x8 a0 = *(bf16x8*)&xlds[(32*w +      c)*40 + 8*g];
        bf16x8 a1 = *(bf16x8*)&xlds[(32*w + 16 + c)*40 + 8*g];
        #pragma unroll
        for (int nf = 0; nf < 4; nf++) {
            bf16x8 bv = *(bf16x8*)&wt[(c + 16*nf)*40 + 8*g];
            acc[0][nf] = mfma16(a0, bv, acc[0][nf]);
            acc[1][nf] = mfma16(a1, bv, acc[1][nf]);
        }
        __syncthreads();
    }
    #pragma unroll
    for (int mi = 0; mi < 2; mi++)
        #pragma unroll
        for (int nf = 0; nf < 4; nf++)
            #pragma unroll
            for (int r = 0; r < 4; r++) {
                int row = mb + 32*w + 16*mi + 4*g + r;
                out[(size_t)row * ND + nb + c + 16*nf] = acc[mi][nf][r];
            }
}

extern "C" void kernel_launch(void* const* d_in, const int* in_sizes, int n_in,
                              void* d_out, int out_size, void* d_ws, size_t ws_size,
                              hipStream_t stream) {
    (void)in_sizes; (void)n_in; (void)out_size; (void)ws_size;
    const float* Q  = (const float*)d_in[0];
    const float* K  = (const float*)d_in[1];
    const float* V  = (const float*)d_in[2];
    const float* WQ = (const float*)d_in[3];
    const float* WK = (const float*)d_in[4];
    const float* WV = (const float*)d_in[5];
    const float* WO = (const float*)d_in[6];

    char* ws = (char*)d_ws;
    const size_t PLANE = (size_t)NB * NH * NS * NDK * 2;   // 8,388,608 B
    short* qhi = (short*)(ws);
    short* qlo = (short*)(ws + PLANE);
    short* khi = (short*)(ws + 2*PLANE);
    short* klo = (short*)(ws + 3*PLANE);
    short* vt  = (short*)(ws + 4*PLANE);
    short* ao  = (short*)(ws + 5*PLANE);

    proj_kernel<<<dim3(64, NH, 3), 256, 0, stream>>>(Q, K, V, WQ, WK, WV,
                                                     qhi, qlo, khi, klo, vt);
    attn_kernel<<<dim3(NB*NH, NS/64), 256, 0, stream>>>(qhi, qlo, khi, klo, vt, ao);
    oproj_kernel<<<dim3(64, ND/NDK), 256, 0, stream>>>(ao, WO, (float*)d_out);
}